// Round 7
// baseline (43318.088 us; speedup 1.0000x reference)
//
#include <hip/hip_runtime.h>
#include <math.h>

// ---------------------------------------------------------------------------
// DefaultHumanoidGRUCritic on MI355X — round 7
//
// Round-6 measured: pin4 asm forced liveness but the allocator SPILLED the 96
// pinned floats to scratch (VGPR=76 < 96; FETCH 0.64->1.02e6 KB; dur +15%).
// Round-5 model refined: step = comm round + weight re-stream, SERIALIZED
// (weight loads sit after the verify spin in program order).
// Round-7:
//   * 48 weight floats/lane (fits natural allocation):
//       A = 32 WGs x 512 thr, 16 el/WG, 32 lanes/element
//       B = 64 WGs x 512 thr,  8 el/WG, 64 lanes/element (ih|hh halves)
//   * weight loads into locals at TOP of each step, BEFORE the spin:
//     hoisted out of loop (residency) or issued pre-spin (overlap) — both fine.
//   * keep: 1 barrier/step, double-buffered LDS, parallel ring probes,
//     ig0 prefetch 1 step ahead. NO pin asm.
// Comm fabric unchanged (proven rounds 2-5): fence-free tagged 8B relaxed
// agent atomics, ring0=2048 slots + coarse cntB throttle, ring1=8 slots.
// ---------------------------------------------------------------------------

#define T_STEPS 16384
#define IN_DIM 341
#define HID 512
#define G3 1536
#define TTILE 16
#define R0 2048
#define R0M (R0-1)
#define R1 8
#define R1M (R1-1)

__device__ __forceinline__ float dot4(float4 a, float4 b) {
  return fmaf(a.x, b.x, fmaf(a.y, b.y, fmaf(a.z, b.z, a.w * b.w)));
}
__device__ __forceinline__ float fast_sigmoid(float x) {
  return __builtin_amdgcn_rcpf(1.0f + __expf(-x));
}
__device__ __forceinline__ float fast_tanh(float x) {
  return fmaf(-2.0f, __builtin_amdgcn_rcpf(1.0f + __expf(2.0f * x)), 1.0f);
}
__device__ __forceinline__ unsigned long long ld_rlx64(const unsigned long long* p) {
  return __hip_atomic_load(p, __ATOMIC_RELAXED, __HIP_MEMORY_SCOPE_AGENT);
}
__device__ __forceinline__ void st_rlx64(unsigned long long* p, unsigned long long v) {
  __hip_atomic_store(p, v, __ATOMIC_RELAXED, __HIP_MEMORY_SCOPE_AGENT);
}
__device__ __forceinline__ unsigned ld_rlx32(const unsigned* p) {
  return __hip_atomic_load(p, __ATOMIC_RELAXED, __HIP_MEMORY_SCOPE_AGENT);
}
__device__ __forceinline__ void st_rlx32(unsigned* p, unsigned v) {
  __hip_atomic_store(p, v, __ATOMIC_RELAXED, __HIP_MEMORY_SCOPE_AGENT);
}
__device__ __forceinline__ unsigned long long pack_tv(unsigned tag, float v) {
  return ((unsigned long long)tag << 32) | (unsigned long long)__float_as_uint(v);
}
// tagged verify load with backoff: fast path = single load when data present
__device__ __forceinline__ float verify_ld(const unsigned long long* p, unsigned want) {
  unsigned long long w = ld_rlx64(p);
  while ((unsigned)(w >> 32) != want) {
    __builtin_amdgcn_s_sleep(1);
    w = ld_rlx64(p);
  }
  return __uint_as_float((unsigned)w);
}

// ---- k0: concat observations ----------------------------------------------
__global__ __launch_bounds__(384) void concat_kernel(
    const float* __restrict__ p0, const float* __restrict__ p1,
    const float* __restrict__ p2, const float* __restrict__ p3,
    const float* __restrict__ p4, const float* __restrict__ p5,
    const float* __restrict__ p6, const float* __restrict__ p7,
    const float* __restrict__ p8, const float* __restrict__ p9,
    const float* __restrict__ p10, const float* __restrict__ p11,
    const float* __restrict__ p12, float* __restrict__ obs) {
  int t = blockIdx.x;
  int k = threadIdx.x;
  if (k >= IN_DIM) return;
  float v;
  if (k < 21)       v = p0[t*21 + k];
  else if (k < 42)  v = p1[t*21 + (k-21)];
  else if (k < 202) v = p2[t*160 + (k-42)];
  else if (k < 298) v = p3[t*96 + (k-202)];
  else if (k < 301) v = p4[t*3 + (k-298)];
  else if (k < 304) v = p5[t*3 + (k-301)];
  else if (k < 325) v = p6[t*21 + (k-304)];
  else if (k < 328) v = p7[t*3 + (k-325)];
  else if (k < 332) v = p8[t*4 + (k-328)];
  else if (k < 335) v = p9[t*3 + (k-332)];
  else if (k < 338) v = p10[t*3 + (k-335)];
  else if (k < 340) v = p11[t*2 + (k-338)];
  else              v = p12[t];
  obs[(size_t)t*IN_DIM + k] = v;
}

// ---- k1: transpose w_ih0 ---------------------------------------------------
__global__ __launch_bounds__(256) void transpose_kernel(const float* __restrict__ w,
                                                        float* __restrict__ wT) {
  __shared__ float tile[32][33];
  int tx = threadIdx.x;  // 32
  int ty = threadIdx.y;  // 8
  int k = blockIdx.x*32 + tx;
#pragma unroll
  for (int jj = 0; jj < 4; jj++) {
    int r = blockIdx.y*32 + ty*4 + jj;
    tile[ty*4+jj][tx] = (k < IN_DIM) ? w[(size_t)r*IN_DIM + k] : 0.f;
  }
  __syncthreads();
#pragma unroll
  for (int jj = 0; jj < 4; jj++) {
    int kk = blockIdx.x*32 + ty*4 + jj;
    if (kk < IN_DIM) wT[(size_t)kk*G3 + blockIdx.y*32 + tx] = tile[tx][ty*4+jj];
  }
}

// ---- k2: IG0 = obs @ w_ih0^T + b_ih0 --------------------------------------
__global__ __launch_bounds__(256) void ig0_kernel(const float* __restrict__ wT,
                                                  const float* __restrict__ obs,
                                                  const float* __restrict__ b_ih0,
                                                  float* __restrict__ ig0) {
  int o = blockIdx.x*256 + threadIdx.x;
  int t0 = blockIdx.y * TTILE;
  float acc[TTILE];
  float b = b_ih0[o];
#pragma unroll
  for (int tt = 0; tt < TTILE; tt++) acc[tt] = b;
  for (int k = 0; k < IN_DIM; k++) {
    float wv = wT[(size_t)k*G3 + o];
#pragma unroll
    for (int tt = 0; tt < TTILE; tt++)
      acc[tt] = fmaf(obs[(size_t)(t0+tt)*IN_DIM + k], wv, acc[tt]);
  }
#pragma unroll
  for (int tt = 0; tt < TTILE; tt++)
    ig0[(size_t)(t0+tt)*G3 + o] = acc[tt];
}

// ---- k_init: seed ring slot 0 with tagged initial hidden -------------------
__global__ __launch_bounds__(512) void init_kernel(const float* __restrict__ hid,
                                                   unsigned long long* ring0,
                                                   unsigned long long* ring1) {
  int e = threadIdx.x;
  st_rlx64(&ring0[e], pack_tv(0u, hid[e]));
  st_rlx64(&ring1[e], pack_tv(0u, hid[HID + e]));
}

// ---- k3: sequential GRU scan ----------------------------------------------
// 96 WGs x 512 threads. WGs [0,32): stage A (layer 0), 16 el/WG, 32 lanes per
// element, 48 weight floats/lane loaded at step top (hoist-or-prefetch).
// WGs [32,96): stage B (layer 1), 8 el/WG, 64 lanes per element split into
// ih half (lanes 0-31, reads h0) and hh half (lanes 32-63, reads h1).
__global__ __launch_bounds__(512, 2) void seq_kernel(
    const float* __restrict__ ig0, const float* __restrict__ w_hh0,
    const float* __restrict__ b_n0, const float* __restrict__ w_ih1,
    const float* __restrict__ w_hh1, const float* __restrict__ b_ih1,
    const float* __restrict__ b_n1,
    unsigned long long* ring0, unsigned long long* ring1, unsigned* cntB,
    float* __restrict__ h1a, float* __restrict__ d_out) {
  __shared__ float hbuf0[2][HID];
  __shared__ float hbuf1[2][HID];
  __shared__ float igbuf[2][48];
  const int tid = threadIdx.x;

  if ((int)blockIdx.x < 32) {
    // ================= stage A: layer-0 GRU =================
    const int wg = blockIdx.x;
    const int g  = tid >> 5;        // 0..15: element
    const int j  = tid & 31;        // K-lane (chunk of 16 floats per gate)
    const int eg = wg*16 + g;       // global h0 element
    const bool leader = (j == 0);
    const int iggate = tid / 16, ige = tid & 15;   // for tid<48 ig prefetch
    const float4* rowr = (const float4*)(w_hh0 + (size_t)eg*HID);
    const float4* rowz = (const float4*)(w_hh0 + (size_t)(512+eg)*HID);
    const float4* rown = (const float4*)(w_hh0 + (size_t)(1024+eg)*HID);
    const float bn = b_n0[eg];
    // preload igbuf for step 0
    if (tid < 48) igbuf[0][tid] = ig0[(size_t)iggate*HID + wg*16 + ige];
    for (int t = 0; t < T_STEPS; t++) {
      const int p = t & 1;
      // weight locals at step top: loop-invariant -> compiler hoists to regs,
      // or at worst issues the loads BEFORE the spin (overlap with comm).
      float4 lr[4], lz[4], ln_[4];
#pragma unroll
      for (int i = 0; i < 4; i++) {
        lr[i] = rowr[j + 32*i]; lz[i] = rowz[j + 32*i]; ln_[i] = rown[j + 32*i];
      }
      // prefetch ig for step t+1 (plain cached load; LDS write after barrier)
      float igpre = 0.f;
      if (tid < 48) {
        int tn = (t+1 < T_STEPS) ? t+1 : t;
        igpre = ig0[(size_t)tn*G3 + iggate*HID + wg*16 + ige];
      }
      // ring-overwrite throttle: steps [t,t+511] overwrite tags <= t+512-R0
      if ((t & 511) == 0 && t >= R0 && tid < 64) {
        const unsigned need = (unsigned)(t + 512 - R0);
        while (true) {
          unsigned v = ld_rlx32(&cntB[tid]);
          if (__ballot(v >= need) == ~0ull) break;
          __builtin_amdgcn_s_sleep(16);
        }
      }
      // stage h0^(t): thread i verifies element i
      hbuf0[p][tid] = verify_ld(&ring0[(size_t)(t & R0M)*HID + tid], (unsigned)t);
      __syncthreads();   // the only barrier per step
      float pr=0.f, pz=0.f, pn=0.f;
      const float4* hp = (const float4*)hbuf0[p];
#pragma unroll
      for (int i = 0; i < 4; i++) {
        float4 hv = hp[j + 32*i];
        pr += dot4(lr[i],hv); pz += dot4(lz[i],hv); pn += dot4(ln_[i],hv);
      }
#pragma unroll
      for (int s = 1; s < 32; s <<= 1) {
        pr += __shfl_xor(pr, s, 32);
        pz += __shfl_xor(pz, s, 32);
        pn += __shfl_xor(pn, s, 32);
      }
      if (leader) {
        float r = fast_sigmoid(igbuf[p][g] + pr);
        float z = fast_sigmoid(igbuf[p][16+g] + pz);
        float n = fast_tanh(igbuf[p][32+g] + r*(pn + bn));
        float hnew = n + z*(hbuf0[p][eg] - n);
        st_rlx64(&ring0[(size_t)((t+1) & R0M)*HID + eg],
                 pack_tv((unsigned)(t+1), hnew));
        if (t == T_STEPS-1) d_out[T_STEPS + eg] = hnew;
      }
      if (tid < 48) igbuf[p ^ 1][tid] = igpre;
    }
  } else {
    // ================= stage B: layer-1 GRU =================
    const int wg  = (int)blockIdx.x - 32;  // 0..63
    const int g   = tid >> 6;              // 0..7: element
    const int l64 = tid & 63;
    const int half = l64 >> 5;             // 0 = ih (reads h0), 1 = hh (reads h1)
    const int j   = l64 & 31;
    const int eg  = wg*8 + g;              // global h1 element
    const bool leader = (l64 == 0);
    const float* Wm = half ? w_hh1 : w_ih1;
    const float4* rowr = (const float4*)(Wm + (size_t)eg*HID);
    const float4* rowz = (const float4*)(Wm + (size_t)(512+eg)*HID);
    const float4* rown = (const float4*)(Wm + (size_t)(1024+eg)*HID);
    const float cr = b_ih1[eg], cz = b_ih1[512+eg], cn = b_ih1[1024+eg];
    const float bnn = b_n1[eg];
    for (int t = 0; t < T_STEPS; t++) {
      const int p = t & 1;
      float4 lr[4], lz[4], ln_[4];
#pragma unroll
      for (int i = 0; i < 4; i++) {
        lr[i] = rowr[j + 32*i]; lz[i] = rowz[j + 32*i]; ln_[i] = rown[j + 32*i];
      }
      // stage h0^(t) [tag t+1] and h1^(t-1) [tag t]; both probes in flight
      const unsigned long long* s0 = &ring0[(size_t)((t+1) & R0M)*HID + tid];
      const unsigned long long* s1 = &ring1[(size_t)(t & R1M)*HID + tid];
      const unsigned w0t = (unsigned)(t+1), w1t = (unsigned)t;
      unsigned long long v0 = ld_rlx64(s0);
      unsigned long long v1 = ld_rlx64(s1);
      while ((unsigned)(v0 >> 32) != w0t) { __builtin_amdgcn_s_sleep(1); v0 = ld_rlx64(s0); }
      while ((unsigned)(v1 >> 32) != w1t) { __builtin_amdgcn_s_sleep(1); v1 = ld_rlx64(s1); }
      hbuf0[p][tid] = __uint_as_float((unsigned)v0);
      hbuf1[p][tid] = __uint_as_float((unsigned)v1);
      __syncthreads();   // the only barrier per step
      const float4* hp = (const float4*)(half ? hbuf1[p] : hbuf0[p]);
      float pr=0.f, pz=0.f, pn=0.f;
#pragma unroll
      for (int i = 0; i < 4; i++) {
        float4 hv = hp[j + 32*i];
        pr += dot4(lr[i],hv); pz += dot4(lz[i],hv); pn += dot4(ln_[i],hv);
      }
#pragma unroll
      for (int s = 1; s < 32; s <<= 1) {   // width 32: halves reduce separately
        pr += __shfl_xor(pr, s, 32);
        pz += __shfl_xor(pz, s, 32);
        pn += __shfl_xor(pn, s, 32);
      }
      // harvest hh-half sums (lane 32 of the 64-lane element group)
      float qr = __shfl(pr, 32, 64);
      float qz = __shfl(pz, 32, 64);
      float qn = __shfl(pn, 32, 64);
      if (leader) {
        float r = fast_sigmoid(pr + cr + qr);
        float z = fast_sigmoid(pz + cz + qz);
        float n = fast_tanh(pn + cn + r*(qn + bnn));
        float hnew = n + z*(hbuf1[p][eg] - n);
        st_rlx64(&ring1[(size_t)((t+1) & R1M)*HID + eg],
                 pack_tv((unsigned)(t+1), hnew));
        h1a[(size_t)t*HID + eg] = hnew;   // plain store for the MLP kernel
        if (t == T_STEPS-1) d_out[T_STEPS + HID + eg] = hnew;
      }
      if (tid == 0 && (t & 31) == 31)
        st_rlx32(&cntB[wg], (unsigned)(t+1));   // throttle progress (coarse)
    }
  }
}

// ---- k4: batched MLP head --------------------------------------------------
__global__ __launch_bounds__(64) void mlp_kernel(
    const float* __restrict__ h1_all, const float* __restrict__ mw0,
    const float* __restrict__ mb0, const float* __restrict__ mw1,
    const float* __restrict__ mb1, const float* __restrict__ mw2,
    const float* __restrict__ mb2, float* __restrict__ out) {
  const int l = threadIdx.x;
  const int t0 = blockIdx.x * 8;
  __shared__ float v0s[8][64];
  float acc[8];
#pragma unroll
  for (int tt = 0; tt < 8; tt++) acc[tt] = mb0[l];
  const float4* w = (const float4*)(mw0 + (size_t)l*512);
#pragma unroll 4
  for (int i = 0; i < 128; i++) {
    float4 a = w[i];
#pragma unroll
    for (int tt = 0; tt < 8; tt++) {
      float4 b = ((const float4*)(h1_all + (size_t)(t0+tt)*512))[i];
      acc[tt] = fmaf(a.x,b.x, fmaf(a.y,b.y, fmaf(a.z,b.z, fmaf(a.w,b.w, acc[tt]))));
    }
  }
#pragma unroll
  for (int tt = 0; tt < 8; tt++) v0s[tt][l] = fmaxf(acc[tt], 0.f);
  __syncthreads();
  float acc1[8];
#pragma unroll
  for (int tt = 0; tt < 8; tt++) acc1[tt] = mb1[l];
  const float* w1 = mw1 + (size_t)l*64;
  for (int jj = 0; jj < 64; jj++) {
    float wv = w1[jj];
#pragma unroll
    for (int tt = 0; tt < 8; tt++) acc1[tt] = fmaf(wv, v0s[tt][jj], acc1[tt]);
  }
  float w2 = mw2[l];
  float bb = mb2[0];
#pragma unroll
  for (int tt = 0; tt < 8; tt++) {
    float y = w2 * fmaxf(acc1[tt], 0.f);
#pragma unroll
    for (int s = 32; s > 0; s >>= 1) y += __shfl_down(y, s, 64);
    if (l == 0) out[t0+tt] = y + bb;
  }
}

// ---------------------------------------------------------------------------
extern "C" void kernel_launch(void* const* d_in, const int* in_sizes, int n_in,
                              void* d_out, int out_size, void* d_ws, size_t ws_size,
                              hipStream_t stream) {
  const float* p0  = (const float*)d_in[0];
  const float* p1  = (const float*)d_in[1];
  const float* p2  = (const float*)d_in[2];
  const float* p3  = (const float*)d_in[3];
  const float* p4  = (const float*)d_in[4];
  const float* p5  = (const float*)d_in[5];
  const float* p6  = (const float*)d_in[6];
  const float* p7  = (const float*)d_in[7];
  const float* p8  = (const float*)d_in[8];
  const float* p9  = (const float*)d_in[9];
  const float* p10 = (const float*)d_in[10];
  const float* p11 = (const float*)d_in[11];
  const float* p12 = (const float*)d_in[12];
  const float* hid   = (const float*)d_in[13];
  const float* w_ih0 = (const float*)d_in[14];
  const float* w_hh0 = (const float*)d_in[15];
  const float* b_ih0 = (const float*)d_in[16];
  const float* b_n0  = (const float*)d_in[17];
  const float* w_ih1 = (const float*)d_in[18];
  const float* w_hh1 = (const float*)d_in[19];
  const float* b_ih1 = (const float*)d_in[20];
  const float* b_n1  = (const float*)d_in[21];
  const float* mw0 = (const float*)d_in[22];
  const float* mb0 = (const float*)d_in[23];
  const float* mw1 = (const float*)d_in[24];
  const float* mb1 = (const float*)d_in[25];
  const float* mw2 = (const float*)d_in[26];
  const float* mb2 = (const float*)d_in[27];
  float* out = (float*)d_out;

  // workspace: ig0 | ring0 | ring1 | cntB | h1a  (obs/wT alias h1a region)
  char* base = (char*)d_ws;
  const size_t IG0_B = (size_t)T_STEPS*G3*4;     // 100,663,296
  const size_t R0_B  = (size_t)R0*HID*8;         //   8,388,608
  const size_t R1_B  = (size_t)R1*HID*8;         //      32,768
  const size_t CNT_B = 1024;
  const size_t H1A_B = (size_t)T_STEPS*HID*4;    //  33,554,432
  float* ig0 = (float*)base;
  unsigned long long* ring0 = (unsigned long long*)(base + IG0_B);
  unsigned long long* ring1 = (unsigned long long*)(base + IG0_B + R0_B);
  unsigned* cntB = (unsigned*)(base + IG0_B + R0_B + R1_B);
  float* h1a = (float*)(base + IG0_B + R0_B + R1_B + CNT_B);
  float* obs = h1a;                                              // alias
  float* wT  = (float*)((char*)h1a + (size_t)T_STEPS*IN_DIM*4);  // alias
  if (ws_size < IG0_B + R0_B + R1_B + CNT_B + H1A_B) return;

  hipMemsetAsync(cntB, 0, CNT_B, stream);
  concat_kernel<<<T_STEPS, 384, 0, stream>>>(p0,p1,p2,p3,p4,p5,p6,p7,p8,p9,p10,p11,p12, obs);
  transpose_kernel<<<dim3(11,48), dim3(32,8), 0, stream>>>(w_ih0, wT);
  ig0_kernel<<<dim3(6, T_STEPS/TTILE), 256, 0, stream>>>(wT, obs, b_ih0, ig0);
  init_kernel<<<1, 512, 0, stream>>>(hid, ring0, ring1);
  seq_kernel<<<96, 512, 0, stream>>>(ig0, w_hh0, b_n0, w_ih1, w_hh1, b_ih1, b_n1,
                                     ring0, ring1, cntB, h1a, out);
  mlp_kernel<<<T_STEPS/8, 64, 0, stream>>>(h1a, mw0, mb0, mw1, mb1, mw2, mb2, out);
}

// Round 8
// 40014.050 us; speedup vs baseline: 1.0826x; 1.0826x over previous
//
#include <hip/hip_runtime.h>
#include <math.h>

// ---------------------------------------------------------------------------
// DefaultHumanoidGRUCritic on MI355X — round 8
//
// Rounds 5-7 saga resolved: the compiler's occupancy-driven VGPR target
// (64/lane, because small LDS implies 4 blocks/CU possible) forced per-step
// weight re-streaming from L2 (~0.73us/step serialized after the comm spin).
// Our grid is 48 WGs on 256 CUs: true occupancy is 1 block/CU regardless.
// Round-8: make the compiler see that —
//   * 96KB __shared__ pad (guarded so it can't be elided) -> occupancy calc
//     says 1 block/CU -> VGPR budget 256/lane
//   * __attribute__((amdgpu_waves_per_eu(1,2))) as the explicit hint
//   * round-5 geometry (best measured): A=16 WGs x 512 (32 el/WG, 16
//     lanes/el), B=32 WGs x 512 (16 el/WG, ih/hh 16-lane halves), 96 weight
//     floats/lane loaded ONCE before the loop (no pin asm)
//   * keep round-6/7 good bits: ONE barrier/step (parity double-buffered
//     LDS), parallel ring probes in B, ig0 prefetch one step ahead
// Comm fabric unchanged (proven): fence-free tagged 8B relaxed agent
// atomics; ring0=2048 slots + coarse cntB throttle; ring1=8 slots.
// ---------------------------------------------------------------------------

#define T_STEPS 16384
#define IN_DIM 341
#define HID 512
#define G3 1536
#define TTILE 16
#define R0 2048
#define R0M (R0-1)
#define R1 8
#define R1M (R1-1)

__device__ __forceinline__ float dot4(float4 a, float4 b) {
  return fmaf(a.x, b.x, fmaf(a.y, b.y, fmaf(a.z, b.z, a.w * b.w)));
}
__device__ __forceinline__ float fast_sigmoid(float x) {
  return __builtin_amdgcn_rcpf(1.0f + __expf(-x));
}
__device__ __forceinline__ float fast_tanh(float x) {
  return fmaf(-2.0f, __builtin_amdgcn_rcpf(1.0f + __expf(2.0f * x)), 1.0f);
}
__device__ __forceinline__ unsigned long long ld_rlx64(const unsigned long long* p) {
  return __hip_atomic_load(p, __ATOMIC_RELAXED, __HIP_MEMORY_SCOPE_AGENT);
}
__device__ __forceinline__ void st_rlx64(unsigned long long* p, unsigned long long v) {
  __hip_atomic_store(p, v, __ATOMIC_RELAXED, __HIP_MEMORY_SCOPE_AGENT);
}
__device__ __forceinline__ unsigned ld_rlx32(const unsigned* p) {
  return __hip_atomic_load(p, __ATOMIC_RELAXED, __HIP_MEMORY_SCOPE_AGENT);
}
__device__ __forceinline__ void st_rlx32(unsigned* p, unsigned v) {
  __hip_atomic_store(p, v, __ATOMIC_RELAXED, __HIP_MEMORY_SCOPE_AGENT);
}
__device__ __forceinline__ unsigned long long pack_tv(unsigned tag, float v) {
  return ((unsigned long long)tag << 32) | (unsigned long long)__float_as_uint(v);
}
// tagged verify load with backoff: fast path = single load when data present
__device__ __forceinline__ float verify_ld(const unsigned long long* p, unsigned want) {
  unsigned long long w = ld_rlx64(p);
  while ((unsigned)(w >> 32) != want) {
    __builtin_amdgcn_s_sleep(1);
    w = ld_rlx64(p);
  }
  return __uint_as_float((unsigned)w);
}

// ---- k0: concat observations ----------------------------------------------
__global__ __launch_bounds__(384) void concat_kernel(
    const float* __restrict__ p0, const float* __restrict__ p1,
    const float* __restrict__ p2, const float* __restrict__ p3,
    const float* __restrict__ p4, const float* __restrict__ p5,
    const float* __restrict__ p6, const float* __restrict__ p7,
    const float* __restrict__ p8, const float* __restrict__ p9,
    const float* __restrict__ p10, const float* __restrict__ p11,
    const float* __restrict__ p12, float* __restrict__ obs) {
  int t = blockIdx.x;
  int k = threadIdx.x;
  if (k >= IN_DIM) return;
  float v;
  if (k < 21)       v = p0[t*21 + k];
  else if (k < 42)  v = p1[t*21 + (k-21)];
  else if (k < 202) v = p2[t*160 + (k-42)];
  else if (k < 298) v = p3[t*96 + (k-202)];
  else if (k < 301) v = p4[t*3 + (k-298)];
  else if (k < 304) v = p5[t*3 + (k-301)];
  else if (k < 325) v = p6[t*21 + (k-304)];
  else if (k < 328) v = p7[t*3 + (k-325)];
  else if (k < 332) v = p8[t*4 + (k-328)];
  else if (k < 335) v = p9[t*3 + (k-332)];
  else if (k < 338) v = p10[t*3 + (k-335)];
  else if (k < 340) v = p11[t*2 + (k-338)];
  else              v = p12[t];
  obs[(size_t)t*IN_DIM + k] = v;
}

// ---- k1: transpose w_ih0 ---------------------------------------------------
__global__ __launch_bounds__(256) void transpose_kernel(const float* __restrict__ w,
                                                        float* __restrict__ wT) {
  __shared__ float tile[32][33];
  int tx = threadIdx.x;  // 32
  int ty = threadIdx.y;  // 8
  int k = blockIdx.x*32 + tx;
#pragma unroll
  for (int jj = 0; jj < 4; jj++) {
    int r = blockIdx.y*32 + ty*4 + jj;
    tile[ty*4+jj][tx] = (k < IN_DIM) ? w[(size_t)r*IN_DIM + k] : 0.f;
  }
  __syncthreads();
#pragma unroll
  for (int jj = 0; jj < 4; jj++) {
    int kk = blockIdx.x*32 + ty*4 + jj;
    if (kk < IN_DIM) wT[(size_t)kk*G3 + blockIdx.y*32 + tx] = tile[tx][ty*4+jj];
  }
}

// ---- k2: IG0 = obs @ w_ih0^T + b_ih0 --------------------------------------
__global__ __launch_bounds__(256) void ig0_kernel(const float* __restrict__ wT,
                                                  const float* __restrict__ obs,
                                                  const float* __restrict__ b_ih0,
                                                  float* __restrict__ ig0) {
  int o = blockIdx.x*256 + threadIdx.x;
  int t0 = blockIdx.y * TTILE;
  float acc[TTILE];
  float b = b_ih0[o];
#pragma unroll
  for (int tt = 0; tt < TTILE; tt++) acc[tt] = b;
  for (int k = 0; k < IN_DIM; k++) {
    float wv = wT[(size_t)k*G3 + o];
#pragma unroll
    for (int tt = 0; tt < TTILE; tt++)
      acc[tt] = fmaf(obs[(size_t)(t0+tt)*IN_DIM + k], wv, acc[tt]);
  }
#pragma unroll
  for (int tt = 0; tt < TTILE; tt++)
    ig0[(size_t)(t0+tt)*G3 + o] = acc[tt];
}

// ---- k_init: seed ring slot 0 with tagged initial hidden -------------------
__global__ __launch_bounds__(512) void init_kernel(const float* __restrict__ hid,
                                                   unsigned long long* ring0,
                                                   unsigned long long* ring1) {
  int e = threadIdx.x;
  st_rlx64(&ring0[e], pack_tv(0u, hid[e]));
  st_rlx64(&ring1[e], pack_tv(0u, hid[HID + e]));
}

// ---- k3: sequential GRU scan ----------------------------------------------
// 48 WGs x 512 threads, forced to 1 block/CU (96KB LDS pad) so the register
// allocator gets a 256-VGPR/lane budget and keeps the 96 weight floats/lane
// resident across the whole T-loop.
__global__ __launch_bounds__(512)
__attribute__((amdgpu_waves_per_eu(1, 2)))
void seq_kernel(
    const float* __restrict__ ig0, const float* __restrict__ w_hh0,
    const float* __restrict__ b_n0, const float* __restrict__ w_ih1,
    const float* __restrict__ w_hh1, const float* __restrict__ b_ih1,
    const float* __restrict__ b_n1,
    unsigned long long* ring0, unsigned long long* ring1, unsigned* cntB,
    float* __restrict__ h1a, float* __restrict__ d_out) {
  __shared__ float hbuf0[2][HID];
  __shared__ float hbuf1[2][HID];
  __shared__ float igbuf[2][96];
  __shared__ float vpad[24576];   // 96KB: forces occupancy calc to 1 block/CU
  const int tid = threadIdx.x;
  if (d_out == nullptr) {         // never true at runtime; defeats LDS elision
    vpad[tid] = (float)tid;
    __syncthreads();
    h1a[tid] = vpad[511 - tid];
  }

  if ((int)blockIdx.x < 16) {
    // ================= stage A: layer-0 GRU =================
    const int wg = blockIdx.x;
    const int g  = tid >> 4;        // 0..31: element group
    const int jj = tid & 15;        // lane within group
    const int eg = wg*32 + g;       // global h0 element
    const bool leader = (jj == 0);
    const int iggate = tid >> 5, ige = tid & 31;  // for tid<96 ig prefetch
    // weights as float4 chunks jj+16*i (conflict-free LDS mapping), loaded
    // ONCE; 96 floats/lane now fit the 256-VGPR budget.
    float4 wr[8], wz[8], wn[8];
    {
      const float4* pr_ = (const float4*)(w_hh0 + (size_t)eg*HID);
      const float4* pz_ = (const float4*)(w_hh0 + (size_t)(512+eg)*HID);
      const float4* pn_ = (const float4*)(w_hh0 + (size_t)(1024+eg)*HID);
#pragma unroll
      for (int i = 0; i < 8; i++) {
        wr[i] = pr_[jj + 16*i]; wz[i] = pz_[jj + 16*i]; wn[i] = pn_[jj + 16*i];
      }
    }
    const float bn = b_n0[eg];
    // preload igbuf for step 0
    if (tid < 96) igbuf[0][tid] = ig0[(size_t)iggate*HID + wg*32 + ige];
    for (int t = 0; t < T_STEPS; t++) {
      const int p = t & 1;
      // prefetch ig for step t+1 (plain cached load; LDS write after barrier)
      float igpre = 0.f;
      if (tid < 96) {
        int tn = (t+1 < T_STEPS) ? t+1 : t;
        igpre = ig0[(size_t)tn*G3 + iggate*HID + wg*32 + ige];
      }
      // ring-overwrite throttle: steps [t,t+511] overwrite tags <= t+512-R0
      if ((t & 511) == 0 && t >= R0 && tid < 64) {
        const unsigned need = (unsigned)(t + 512 - R0);
        while (true) {
          unsigned v = ld_rlx32(&cntB[tid & 31]);
          if (__ballot(v >= need) == ~0ull) break;
          __builtin_amdgcn_s_sleep(16);
        }
      }
      // stage h0^(t): thread i verifies element i
      hbuf0[p][tid] = verify_ld(&ring0[(size_t)(t & R0M)*HID + tid], (unsigned)t);
      __syncthreads();   // the only barrier per step
      float pr=0.f, pz=0.f, pn=0.f;
      const float4* hp = (const float4*)hbuf0[p];
#pragma unroll
      for (int i = 0; i < 8; i++) {
        float4 hv = hp[jj + 16*i];   // words 4jj+64i: conflict-free
        pr += dot4(wr[i],hv); pz += dot4(wz[i],hv); pn += dot4(wn[i],hv);
      }
#pragma unroll
      for (int s = 1; s < 16; s <<= 1) {
        pr += __shfl_xor(pr, s, 16);
        pz += __shfl_xor(pz, s, 16);
        pn += __shfl_xor(pn, s, 16);
      }
      if (leader) {
        float r = fast_sigmoid(igbuf[p][g] + pr);
        float z = fast_sigmoid(igbuf[p][32+g] + pz);
        float n = fast_tanh(igbuf[p][64+g] + r*(pn + bn));
        float hnew = n + z*(hbuf0[p][eg] - n);
        st_rlx64(&ring0[(size_t)((t+1) & R0M)*HID + eg],
                 pack_tv((unsigned)(t+1), hnew));
        if (t == T_STEPS-1) d_out[T_STEPS + eg] = hnew;
      }
      if (tid < 96) igbuf[p ^ 1][tid] = igpre;
    }
  } else {
    // ================= stage B: layer-1 GRU =================
    const int wg  = (int)blockIdx.x - 16;  // 0..31
    const int g   = tid >> 5;              // 0..15: element group
    const int j32 = tid & 31;
    const int half = j32 >> 4;             // 0 = ih (reads h0), 1 = hh (reads h1)
    const int jj  = j32 & 15;
    const int eg  = wg*16 + g;             // global h1 element
    const bool leader = (j32 == 0);
    const float* Wm = half ? w_hh1 : w_ih1;
    float4 ar[8], az[8], an[8];
    {
      const float4* pr_ = (const float4*)(Wm + (size_t)eg*HID);
      const float4* pz_ = (const float4*)(Wm + (size_t)(512+eg)*HID);
      const float4* pn_ = (const float4*)(Wm + (size_t)(1024+eg)*HID);
#pragma unroll
      for (int i = 0; i < 8; i++) {
        ar[i] = pr_[jj + 16*i]; az[i] = pz_[jj + 16*i]; an[i] = pn_[jj + 16*i];
      }
    }
    const float cr = b_ih1[eg], cz = b_ih1[512+eg], cn = b_ih1[1024+eg];
    const float bnn = b_n1[eg];
    for (int t = 0; t < T_STEPS; t++) {
      const int p = t & 1;
      // stage h0^(t) [tag t+1] and h1^(t-1) [tag t]; both probes in flight
      const unsigned long long* s0 = &ring0[(size_t)((t+1) & R0M)*HID + tid];
      const unsigned long long* s1 = &ring1[(size_t)(t & R1M)*HID + tid];
      const unsigned w0t = (unsigned)(t+1), w1t = (unsigned)t;
      unsigned long long v0 = ld_rlx64(s0);
      unsigned long long v1 = ld_rlx64(s1);
      while ((unsigned)(v0 >> 32) != w0t) { __builtin_amdgcn_s_sleep(1); v0 = ld_rlx64(s0); }
      while ((unsigned)(v1 >> 32) != w1t) { __builtin_amdgcn_s_sleep(1); v1 = ld_rlx64(s1); }
      hbuf0[p][tid] = __uint_as_float((unsigned)v0);
      hbuf1[p][tid] = __uint_as_float((unsigned)v1);
      __syncthreads();   // the only barrier per step
      const float4* hp = (const float4*)(half ? hbuf1[p] : hbuf0[p]);
      float pr=0.f, pz=0.f, pn=0.f;
#pragma unroll
      for (int i = 0; i < 8; i++) {
        float4 hv = hp[jj + 16*i];
        pr += dot4(ar[i],hv); pz += dot4(az[i],hv); pn += dot4(an[i],hv);
      }
#pragma unroll
      for (int s = 1; s < 16; s <<= 1) {   // width 16: halves reduce separately
        pr += __shfl_xor(pr, s, 16);
        pz += __shfl_xor(pz, s, 16);
        pn += __shfl_xor(pn, s, 16);
      }
      // harvest hh-half sums (lane 16 of the 32-lane group)
      float qr = __shfl(pr, 16, 32);
      float qz = __shfl(pz, 16, 32);
      float qn = __shfl(pn, 16, 32);
      if (leader) {
        float r = fast_sigmoid(pr + cr + qr);
        float z = fast_sigmoid(pz + cz + qz);
        float n = fast_tanh(pn + cn + r*(qn + bnn));
        float hnew = n + z*(hbuf1[p][eg] - n);
        st_rlx64(&ring1[(size_t)((t+1) & R1M)*HID + eg],
                 pack_tv((unsigned)(t+1), hnew));
        h1a[(size_t)t*HID + eg] = hnew;   // plain store for the MLP kernel
        if (t == T_STEPS-1) d_out[T_STEPS + HID + eg] = hnew;
      }
      if (tid == 0 && (t & 31) == 31)
        st_rlx32(&cntB[wg], (unsigned)(t+1));   // throttle progress (coarse)
    }
  }
}

// ---- k4: batched MLP head --------------------------------------------------
__global__ __launch_bounds__(64) void mlp_kernel(
    const float* __restrict__ h1_all, const float* __restrict__ mw0,
    const float* __restrict__ mb0, const float* __restrict__ mw1,
    const float* __restrict__ mb1, const float* __restrict__ mw2,
    const float* __restrict__ mb2, float* __restrict__ out) {
  const int l = threadIdx.x;
  const int t0 = blockIdx.x * 8;
  __shared__ float v0s[8][64];
  float acc[8];
#pragma unroll
  for (int tt = 0; tt < 8; tt++) acc[tt] = mb0[l];
  const float4* w = (const float4*)(mw0 + (size_t)l*512);
#pragma unroll 4
  for (int i = 0; i < 128; i++) {
    float4 a = w[i];
#pragma unroll
    for (int tt = 0; tt < 8; tt++) {
      float4 b = ((const float4*)(h1_all + (size_t)(t0+tt)*512))[i];
      acc[tt] = fmaf(a.x,b.x, fmaf(a.y,b.y, fmaf(a.z,b.z, fmaf(a.w,b.w, acc[tt]))));
    }
  }
#pragma unroll
  for (int tt = 0; tt < 8; tt++) v0s[tt][l] = fmaxf(acc[tt], 0.f);
  __syncthreads();
  float acc1[8];
#pragma unroll
  for (int tt = 0; tt < 8; tt++) acc1[tt] = mb1[l];
  const float* w1 = mw1 + (size_t)l*64;
  for (int jj = 0; jj < 64; jj++) {
    float wv = w1[jj];
#pragma unroll
    for (int tt = 0; tt < 8; tt++) acc1[tt] = fmaf(wv, v0s[tt][jj], acc1[tt]);
  }
  float w2 = mw2[l];
  float bb = mb2[0];
#pragma unroll
  for (int tt = 0; tt < 8; tt++) {
    float y = w2 * fmaxf(acc1[tt], 0.f);
#pragma unroll
    for (int s = 32; s > 0; s >>= 1) y += __shfl_down(y, s, 64);
    if (l == 0) out[t0+tt] = y + bb;
  }
}

// ---------------------------------------------------------------------------
extern "C" void kernel_launch(void* const* d_in, const int* in_sizes, int n_in,
                              void* d_out, int out_size, void* d_ws, size_t ws_size,
                              hipStream_t stream) {
  const float* p0  = (const float*)d_in[0];
  const float* p1  = (const float*)d_in[1];
  const float* p2  = (const float*)d_in[2];
  const float* p3  = (const float*)d_in[3];
  const float* p4  = (const float*)d_in[4];
  const float* p5  = (const float*)d_in[5];
  const float* p6  = (const float*)d_in[6];
  const float* p7  = (const float*)d_in[7];
  const float* p8  = (const float*)d_in[8];
  const float* p9  = (const float*)d_in[9];
  const float* p10 = (const float*)d_in[10];
  const float* p11 = (const float*)d_in[11];
  const float* p12 = (const float*)d_in[12];
  const float* hid   = (const float*)d_in[13];
  const float* w_ih0 = (const float*)d_in[14];
  const float* w_hh0 = (const float*)d_in[15];
  const float* b_ih0 = (const float*)d_in[16];
  const float* b_n0  = (const float*)d_in[17];
  const float* w_ih1 = (const float*)d_in[18];
  const float* w_hh1 = (const float*)d_in[19];
  const float* b_ih1 = (const float*)d_in[20];
  const float* b_n1  = (const float*)d_in[21];
  const float* mw0 = (const float*)d_in[22];
  const float* mb0 = (const float*)d_in[23];
  const float* mw1 = (const float*)d_in[24];
  const float* mb1 = (const float*)d_in[25];
  const float* mw2 = (const float*)d_in[26];
  const float* mb2 = (const float*)d_in[27];
  float* out = (float*)d_out;

  // workspace: ig0 | ring0 | ring1 | cntB | h1a  (obs/wT alias h1a region)
  char* base = (char*)d_ws;
  const size_t IG0_B = (size_t)T_STEPS*G3*4;     // 100,663,296
  const size_t R0_B  = (size_t)R0*HID*8;         //   8,388,608
  const size_t R1_B  = (size_t)R1*HID*8;         //      32,768
  const size_t CNT_B = 1024;
  const size_t H1A_B = (size_t)T_STEPS*HID*4;    //  33,554,432
  float* ig0 = (float*)base;
  unsigned long long* ring0 = (unsigned long long*)(base + IG0_B);
  unsigned long long* ring1 = (unsigned long long*)(base + IG0_B + R0_B);
  unsigned* cntB = (unsigned*)(base + IG0_B + R0_B + R1_B);
  float* h1a = (float*)(base + IG0_B + R0_B + R1_B + CNT_B);
  float* obs = h1a;                                              // alias
  float* wT  = (float*)((char*)h1a + (size_t)T_STEPS*IN_DIM*4);  // alias
  if (ws_size < IG0_B + R0_B + R1_B + CNT_B + H1A_B) return;

  hipMemsetAsync(cntB, 0, CNT_B, stream);
  concat_kernel<<<T_STEPS, 384, 0, stream>>>(p0,p1,p2,p3,p4,p5,p6,p7,p8,p9,p10,p11,p12, obs);
  transpose_kernel<<<dim3(11,48), dim3(32,8), 0, stream>>>(w_ih0, wT);
  ig0_kernel<<<dim3(6, T_STEPS/TTILE), 256, 0, stream>>>(wT, obs, b_ih0, ig0);
  init_kernel<<<1, 512, 0, stream>>>(hid, ring0, ring1);
  seq_kernel<<<48, 512, 0, stream>>>(ig0, w_hh0, b_n0, w_ih1, w_hh1, b_ih1, b_n1,
                                     ring0, ring1, cntB, h1a, out);
  mlp_kernel<<<T_STEPS/8, 64, 0, stream>>>(h1a, mw0, mb0, mw1, mb1, mw2, mb2, out);
}

// Round 9
// 34588.983 us; speedup vs baseline: 1.2524x; 1.1568x over previous
//
#include <hip/hip_runtime.h>
#include <math.h>

// ---------------------------------------------------------------------------
// DefaultHumanoidGRUCritic on MI355X — round 9
//
// The rounds 5-8 weight-residency matrix:
//   r6: pin WITHOUT budget (64-VGPR target) -> scratch spill, FETCH up, slower
//   r8: budget (pad+attr, 256 avail) WITHOUT pin -> loads sunk anyway, VGPR=88
// Round 9 = pin AND budget:
//   * 256-thread blocks, amdgpu_waves_per_eu(1,1), 96KB LDS pad
//     -> 1 wave/EU -> 512-VGPR/lane budget
//   * pin4 asm on all 24 weight float4s -> liveness forced, no spill escape
//   * A = 32 WGs (16 el/WG, 16 lanes/el), B = 64 WGs (8 el/WG, ih/hh halves)
//     = 96 WGs on 256 CUs, 1 block/CU; staging 2 verify words/thread/ring
// Comm fabric unchanged (proven r2-r8): fence-free tagged 8B relaxed agent
// atomics; ring0=2048 slots + coarse cntB throttle; ring1=8 slots; one
// barrier/step; parity-double-buffered LDS; ig0 prefetch one step ahead.
// ---------------------------------------------------------------------------

#define T_STEPS 16384
#define IN_DIM 341
#define HID 512
#define G3 1536
#define TTILE 16
#define R0 2048
#define R0M (R0-1)
#define R1 8
#define R1M (R1-1)

__device__ __forceinline__ float dot4(float4 a, float4 b) {
  return fmaf(a.x, b.x, fmaf(a.y, b.y, fmaf(a.z, b.z, a.w * b.w)));
}
__device__ __forceinline__ float fast_sigmoid(float x) {
  return __builtin_amdgcn_rcpf(1.0f + __expf(-x));
}
__device__ __forceinline__ float fast_tanh(float x) {
  return fmaf(-2.0f, __builtin_amdgcn_rcpf(1.0f + __expf(2.0f * x)), 1.0f);
}
__device__ __forceinline__ unsigned long long ld_rlx64(const unsigned long long* p) {
  return __hip_atomic_load(p, __ATOMIC_RELAXED, __HIP_MEMORY_SCOPE_AGENT);
}
__device__ __forceinline__ void st_rlx64(unsigned long long* p, unsigned long long v) {
  __hip_atomic_store(p, v, __ATOMIC_RELAXED, __HIP_MEMORY_SCOPE_AGENT);
}
__device__ __forceinline__ unsigned ld_rlx32(const unsigned* p) {
  return __hip_atomic_load(p, __ATOMIC_RELAXED, __HIP_MEMORY_SCOPE_AGENT);
}
__device__ __forceinline__ void st_rlx32(unsigned* p, unsigned v) {
  __hip_atomic_store(p, v, __ATOMIC_RELAXED, __HIP_MEMORY_SCOPE_AGENT);
}
__device__ __forceinline__ unsigned long long pack_tv(unsigned tag, float v) {
  return ((unsigned long long)tag << 32) | (unsigned long long)__float_as_uint(v);
}
// pin a float4's components into VGPRs: value becomes asm-defined; the
// compiler can neither re-load nor rematerialize it. With the 512-VGPR
// budget (1 wave/EU) there is no spill pressure either.
__device__ __forceinline__ void pin4(float4& v) {
  asm volatile("" : "+v"(v.x), "+v"(v.y), "+v"(v.z), "+v"(v.w));
}
// tagged verify load with backoff: fast path = single load when data present
__device__ __forceinline__ float verify_ld(const unsigned long long* p, unsigned want) {
  unsigned long long w = ld_rlx64(p);
  while ((unsigned)(w >> 32) != want) {
    __builtin_amdgcn_s_sleep(1);
    w = ld_rlx64(p);
  }
  return __uint_as_float((unsigned)w);
}

// ---- k0: concat observations ----------------------------------------------
__global__ __launch_bounds__(384) void concat_kernel(
    const float* __restrict__ p0, const float* __restrict__ p1,
    const float* __restrict__ p2, const float* __restrict__ p3,
    const float* __restrict__ p4, const float* __restrict__ p5,
    const float* __restrict__ p6, const float* __restrict__ p7,
    const float* __restrict__ p8, const float* __restrict__ p9,
    const float* __restrict__ p10, const float* __restrict__ p11,
    const float* __restrict__ p12, float* __restrict__ obs) {
  int t = blockIdx.x;
  int k = threadIdx.x;
  if (k >= IN_DIM) return;
  float v;
  if (k < 21)       v = p0[t*21 + k];
  else if (k < 42)  v = p1[t*21 + (k-21)];
  else if (k < 202) v = p2[t*160 + (k-42)];
  else if (k < 298) v = p3[t*96 + (k-202)];
  else if (k < 301) v = p4[t*3 + (k-298)];
  else if (k < 304) v = p5[t*3 + (k-301)];
  else if (k < 325) v = p6[t*21 + (k-304)];
  else if (k < 328) v = p7[t*3 + (k-325)];
  else if (k < 332) v = p8[t*4 + (k-328)];
  else if (k < 335) v = p9[t*3 + (k-332)];
  else if (k < 338) v = p10[t*3 + (k-335)];
  else if (k < 340) v = p11[t*2 + (k-338)];
  else              v = p12[t];
  obs[(size_t)t*IN_DIM + k] = v;
}

// ---- k1: transpose w_ih0 ---------------------------------------------------
__global__ __launch_bounds__(256) void transpose_kernel(const float* __restrict__ w,
                                                        float* __restrict__ wT) {
  __shared__ float tile[32][33];
  int tx = threadIdx.x;  // 32
  int ty = threadIdx.y;  // 8
  int k = blockIdx.x*32 + tx;
#pragma unroll
  for (int jj = 0; jj < 4; jj++) {
    int r = blockIdx.y*32 + ty*4 + jj;
    tile[ty*4+jj][tx] = (k < IN_DIM) ? w[(size_t)r*IN_DIM + k] : 0.f;
  }
  __syncthreads();
#pragma unroll
  for (int jj = 0; jj < 4; jj++) {
    int kk = blockIdx.x*32 + ty*4 + jj;
    if (kk < IN_DIM) wT[(size_t)kk*G3 + blockIdx.y*32 + tx] = tile[tx][ty*4+jj];
  }
}

// ---- k2: IG0 = obs @ w_ih0^T + b_ih0 --------------------------------------
__global__ __launch_bounds__(256) void ig0_kernel(const float* __restrict__ wT,
                                                  const float* __restrict__ obs,
                                                  const float* __restrict__ b_ih0,
                                                  float* __restrict__ ig0) {
  int o = blockIdx.x*256 + threadIdx.x;
  int t0 = blockIdx.y * TTILE;
  float acc[TTILE];
  float b = b_ih0[o];
#pragma unroll
  for (int tt = 0; tt < TTILE; tt++) acc[tt] = b;
  for (int k = 0; k < IN_DIM; k++) {
    float wv = wT[(size_t)k*G3 + o];
#pragma unroll
    for (int tt = 0; tt < TTILE; tt++)
      acc[tt] = fmaf(obs[(size_t)(t0+tt)*IN_DIM + k], wv, acc[tt]);
  }
#pragma unroll
  for (int tt = 0; tt < TTILE; tt++)
    ig0[(size_t)(t0+tt)*G3 + o] = acc[tt];
}

// ---- k_init: seed ring slot 0 with tagged initial hidden -------------------
__global__ __launch_bounds__(512) void init_kernel(const float* __restrict__ hid,
                                                   unsigned long long* ring0,
                                                   unsigned long long* ring1) {
  int e = threadIdx.x;
  st_rlx64(&ring0[e], pack_tv(0u, hid[e]));
  st_rlx64(&ring1[e], pack_tv(0u, hid[HID + e]));
}

// ---- k3: sequential GRU scan ----------------------------------------------
// 96 WGs x 256 threads, 1 block/CU (96KB LDS pad) + 1 wave/EU (waves_per_eu
// (1,1)) -> 512-VGPR/lane budget; weights pinned resident via pin4.
__global__ __launch_bounds__(256)
__attribute__((amdgpu_waves_per_eu(1, 1)))
void seq_kernel(
    const float* __restrict__ ig0, const float* __restrict__ w_hh0,
    const float* __restrict__ b_n0, const float* __restrict__ w_ih1,
    const float* __restrict__ w_hh1, const float* __restrict__ b_ih1,
    const float* __restrict__ b_n1,
    unsigned long long* ring0, unsigned long long* ring1, unsigned* cntB,
    float* __restrict__ h1a, float* __restrict__ d_out) {
  __shared__ float hbuf0[2][HID];
  __shared__ float hbuf1[2][HID];
  __shared__ float igbuf[2][48];
  __shared__ float vpad[24576];   // 96KB: forces occupancy calc to 1 block/CU
  const int tid = threadIdx.x;
  if (d_out == nullptr) {         // never true at runtime; defeats LDS elision
    vpad[tid] = (float)tid;
    __syncthreads();
    h1a[tid] = vpad[255 - tid];
  }

  if ((int)blockIdx.x < 32) {
    // ================= stage A: layer-0 GRU =================
    const int wg = blockIdx.x;
    const int g  = tid >> 4;        // 0..15: element group
    const int jj = tid & 15;        // lane within group
    const int eg = wg*16 + g;       // global h0 element
    const bool leader = (jj == 0);
    const int iggate = tid / 16, ige = tid & 15;  // for tid<48 ig prefetch
    // weights as float4 chunks jj+16*i (conflict-free LDS mapping), loaded
    // ONCE and pinned resident (96 floats/lane, 512-VGPR budget).
    float4 wr[8], wz[8], wn[8];
    {
      const float4* pr_ = (const float4*)(w_hh0 + (size_t)eg*HID);
      const float4* pz_ = (const float4*)(w_hh0 + (size_t)(512+eg)*HID);
      const float4* pn_ = (const float4*)(w_hh0 + (size_t)(1024+eg)*HID);
#pragma unroll
      for (int i = 0; i < 8; i++) {
        wr[i] = pr_[jj + 16*i]; wz[i] = pz_[jj + 16*i]; wn[i] = pn_[jj + 16*i];
        pin4(wr[i]); pin4(wz[i]); pin4(wn[i]);
      }
    }
    const float bn = b_n0[eg];
    // preload igbuf for step 0
    if (tid < 48) igbuf[0][tid] = ig0[(size_t)iggate*HID + wg*16 + ige];
    for (int t = 0; t < T_STEPS; t++) {
      const int p = t & 1;
      // prefetch ig for step t+1 (plain cached load; LDS write after barrier)
      float igpre = 0.f;
      if (tid < 48) {
        int tn = (t+1 < T_STEPS) ? t+1 : t;
        igpre = ig0[(size_t)tn*G3 + iggate*HID + wg*16 + ige];
      }
      // ring-overwrite throttle: steps [t,t+511] overwrite tags <= t+512-R0
      if ((t & 511) == 0 && t >= R0 && tid < 64) {
        const unsigned need = (unsigned)(t + 512 - R0);
        while (true) {
          unsigned v = ld_rlx32(&cntB[tid]);
          if (__ballot(v >= need) == ~0ull) break;
          __builtin_amdgcn_s_sleep(16);
        }
      }
      // stage h0^(t): thread i verifies elements i, i+256
      {
        const unsigned long long* slot = ring0 + (size_t)(t & R0M)*HID;
        hbuf0[p][tid]     = verify_ld(&slot[tid], (unsigned)t);
        hbuf0[p][tid+256] = verify_ld(&slot[tid+256], (unsigned)t);
      }
      __syncthreads();   // the only barrier per step
      float pr=0.f, pz=0.f, pn=0.f;
      const float4* hp = (const float4*)hbuf0[p];
#pragma unroll
      for (int i = 0; i < 8; i++) {
        float4 hv = hp[jj + 16*i];   // words 4jj+64i: conflict-free
        pr += dot4(wr[i],hv); pz += dot4(wz[i],hv); pn += dot4(wn[i],hv);
      }
#pragma unroll
      for (int s = 1; s < 16; s <<= 1) {
        pr += __shfl_xor(pr, s, 16);
        pz += __shfl_xor(pz, s, 16);
        pn += __shfl_xor(pn, s, 16);
      }
      if (leader) {
        float r = fast_sigmoid(igbuf[p][g] + pr);
        float z = fast_sigmoid(igbuf[p][16+g] + pz);
        float n = fast_tanh(igbuf[p][32+g] + r*(pn + bn));
        float hnew = n + z*(hbuf0[p][eg] - n);
        st_rlx64(&ring0[(size_t)((t+1) & R0M)*HID + eg],
                 pack_tv((unsigned)(t+1), hnew));
        if (t == T_STEPS-1) d_out[T_STEPS + eg] = hnew;
      }
      if (tid < 48) igbuf[p ^ 1][tid] = igpre;
    }
  } else {
    // ================= stage B: layer-1 GRU =================
    const int wg  = (int)blockIdx.x - 32;  // 0..63
    const int g   = tid >> 5;              // 0..7: element group
    const int j32 = tid & 31;
    const int half = j32 >> 4;             // 0 = ih (reads h0), 1 = hh (reads h1)
    const int jj  = j32 & 15;
    const int eg  = wg*8 + g;              // global h1 element
    const bool leader = (j32 == 0);
    const float* Wm = half ? w_hh1 : w_ih1;
    float4 ar[8], az[8], an[8];
    {
      const float4* pr_ = (const float4*)(Wm + (size_t)eg*HID);
      const float4* pz_ = (const float4*)(Wm + (size_t)(512+eg)*HID);
      const float4* pn_ = (const float4*)(Wm + (size_t)(1024+eg)*HID);
#pragma unroll
      for (int i = 0; i < 8; i++) {
        ar[i] = pr_[jj + 16*i]; az[i] = pz_[jj + 16*i]; an[i] = pn_[jj + 16*i];
        pin4(ar[i]); pin4(az[i]); pin4(an[i]);
      }
    }
    const float cr = b_ih1[eg], cz = b_ih1[512+eg], cn = b_ih1[1024+eg];
    const float bnn = b_n1[eg];
    for (int t = 0; t < T_STEPS; t++) {
      const int p = t & 1;
      // stage h0^(t) [tag t+1] and h1^(t-1) [tag t]; all probes in flight
      const unsigned long long* s0 = ring0 + (size_t)((t+1) & R0M)*HID;
      const unsigned long long* s1 = ring1 + (size_t)(t & R1M)*HID;
      const unsigned w0t = (unsigned)(t+1), w1t = (unsigned)t;
      unsigned long long a0 = ld_rlx64(&s0[tid]);
      unsigned long long a1 = ld_rlx64(&s0[tid+256]);
      unsigned long long b0 = ld_rlx64(&s1[tid]);
      unsigned long long b1 = ld_rlx64(&s1[tid+256]);
      while ((unsigned)(a0 >> 32) != w0t) { __builtin_amdgcn_s_sleep(1); a0 = ld_rlx64(&s0[tid]); }
      while ((unsigned)(a1 >> 32) != w0t) { __builtin_amdgcn_s_sleep(1); a1 = ld_rlx64(&s0[tid+256]); }
      while ((unsigned)(b0 >> 32) != w1t) { __builtin_amdgcn_s_sleep(1); b0 = ld_rlx64(&s1[tid]); }
      while ((unsigned)(b1 >> 32) != w1t) { __builtin_amdgcn_s_sleep(1); b1 = ld_rlx64(&s1[tid+256]); }
      hbuf0[p][tid]     = __uint_as_float((unsigned)a0);
      hbuf0[p][tid+256] = __uint_as_float((unsigned)a1);
      hbuf1[p][tid]     = __uint_as_float((unsigned)b0);
      hbuf1[p][tid+256] = __uint_as_float((unsigned)b1);
      __syncthreads();   // the only barrier per step
      const float4* hp = (const float4*)(half ? hbuf1[p] : hbuf0[p]);
      float pr=0.f, pz=0.f, pn=0.f;
#pragma unroll
      for (int i = 0; i < 8; i++) {
        float4 hv = hp[jj + 16*i];
        pr += dot4(ar[i],hv); pz += dot4(az[i],hv); pn += dot4(an[i],hv);
      }
#pragma unroll
      for (int s = 1; s < 16; s <<= 1) {   // width 16: halves reduce separately
        pr += __shfl_xor(pr, s, 16);
        pz += __shfl_xor(pz, s, 16);
        pn += __shfl_xor(pn, s, 16);
      }
      // harvest hh-half sums (lane 16 of the 32-lane group)
      float qr = __shfl(pr, 16, 32);
      float qz = __shfl(pz, 16, 32);
      float qn = __shfl(pn, 16, 32);
      if (leader) {
        float r = fast_sigmoid(pr + cr + qr);
        float z = fast_sigmoid(pz + cz + qz);
        float n = fast_tanh(pn + cn + r*(qn + bnn));
        float hnew = n + z*(hbuf1[p][eg] - n);
        st_rlx64(&ring1[(size_t)((t+1) & R1M)*HID + eg],
                 pack_tv((unsigned)(t+1), hnew));
        h1a[(size_t)t*HID + eg] = hnew;   // plain store for the MLP kernel
        if (t == T_STEPS-1) d_out[T_STEPS + HID + eg] = hnew;
      }
      if (tid == 0 && (t & 31) == 31)
        st_rlx32(&cntB[wg], (unsigned)(t+1));   // throttle progress (coarse)
    }
  }
}

// ---- k4: batched MLP head --------------------------------------------------
__global__ __launch_bounds__(64) void mlp_kernel(
    const float* __restrict__ h1_all, const float* __restrict__ mw0,
    const float* __restrict__ mb0, const float* __restrict__ mw1,
    const float* __restrict__ mb1, const float* __restrict__ mw2,
    const float* __restrict__ mb2, float* __restrict__ out) {
  const int l = threadIdx.x;
  const int t0 = blockIdx.x * 8;
  __shared__ float v0s[8][64];
  float acc[8];
#pragma unroll
  for (int tt = 0; tt < 8; tt++) acc[tt] = mb0[l];
  const float4* w = (const float4*)(mw0 + (size_t)l*512);
#pragma unroll 4
  for (int i = 0; i < 128; i++) {
    float4 a = w[i];
#pragma unroll
    for (int tt = 0; tt < 8; tt++) {
      float4 b = ((const float4*)(h1_all + (size_t)(t0+tt)*512))[i];
      acc[tt] = fmaf(a.x,b.x, fmaf(a.y,b.y, fmaf(a.z,b.z, fmaf(a.w,b.w, acc[tt]))));
    }
  }
#pragma unroll
  for (int tt = 0; tt < 8; tt++) v0s[tt][l] = fmaxf(acc[tt], 0.f);
  __syncthreads();
  float acc1[8];
#pragma unroll
  for (int tt = 0; tt < 8; tt++) acc1[tt] = mb1[l];
  const float* w1 = mw1 + (size_t)l*64;
  for (int jj = 0; jj < 64; jj++) {
    float wv = w1[jj];
#pragma unroll
    for (int tt = 0; tt < 8; tt++) acc1[tt] = fmaf(wv, v0s[tt][jj], acc1[tt]);
  }
  float w2 = mw2[l];
  float bb = mb2[0];
#pragma unroll
  for (int tt = 0; tt < 8; tt++) {
    float y = w2 * fmaxf(acc1[tt], 0.f);
#pragma unroll
    for (int s = 32; s > 0; s >>= 1) y += __shfl_down(y, s, 64);
    if (l == 0) out[t0+tt] = y + bb;
  }
}

// ---------------------------------------------------------------------------
extern "C" void kernel_launch(void* const* d_in, const int* in_sizes, int n_in,
                              void* d_out, int out_size, void* d_ws, size_t ws_size,
                              hipStream_t stream) {
  const float* p0  = (const float*)d_in[0];
  const float* p1  = (const float*)d_in[1];
  const float* p2  = (const float*)d_in[2];
  const float* p3  = (const float*)d_in[3];
  const float* p4  = (const float*)d_in[4];
  const float* p5  = (const float*)d_in[5];
  const float* p6  = (const float*)d_in[6];
  const float* p7  = (const float*)d_in[7];
  const float* p8  = (const float*)d_in[8];
  const float* p9  = (const float*)d_in[9];
  const float* p10 = (const float*)d_in[10];
  const float* p11 = (const float*)d_in[11];
  const float* p12 = (const float*)d_in[12];
  const float* hid   = (const float*)d_in[13];
  const float* w_ih0 = (const float*)d_in[14];
  const float* w_hh0 = (const float*)d_in[15];
  const float* b_ih0 = (const float*)d_in[16];
  const float* b_n0  = (const float*)d_in[17];
  const float* w_ih1 = (const float*)d_in[18];
  const float* w_hh1 = (const float*)d_in[19];
  const float* b_ih1 = (const float*)d_in[20];
  const float* b_n1  = (const float*)d_in[21];
  const float* mw0 = (const float*)d_in[22];
  const float* mb0 = (const float*)d_in[23];
  const float* mw1 = (const float*)d_in[24];
  const float* mb1 = (const float*)d_in[25];
  const float* mw2 = (const float*)d_in[26];
  const float* mb2 = (const float*)d_in[27];
  float* out = (float*)d_out;

  // workspace: ig0 | ring0 | ring1 | cntB | h1a  (obs/wT alias h1a region)
  char* base = (char*)d_ws;
  const size_t IG0_B = (size_t)T_STEPS*G3*4;     // 100,663,296
  const size_t R0_B  = (size_t)R0*HID*8;         //   8,388,608
  const size_t R1_B  = (size_t)R1*HID*8;         //      32,768
  const size_t CNT_B = 1024;
  const size_t H1A_B = (size_t)T_STEPS*HID*4;    //  33,554,432
  float* ig0 = (float*)base;
  unsigned long long* ring0 = (unsigned long long*)(base + IG0_B);
  unsigned long long* ring1 = (unsigned long long*)(base + IG0_B + R0_B);
  unsigned* cntB = (unsigned*)(base + IG0_B + R0_B + R1_B);
  float* h1a = (float*)(base + IG0_B + R0_B + R1_B + CNT_B);
  float* obs = h1a;                                              // alias
  float* wT  = (float*)((char*)h1a + (size_t)T_STEPS*IN_DIM*4);  // alias
  if (ws_size < IG0_B + R0_B + R1_B + CNT_B + H1A_B) return;

  hipMemsetAsync(cntB, 0, CNT_B, stream);
  concat_kernel<<<T_STEPS, 384, 0, stream>>>(p0,p1,p2,p3,p4,p5,p6,p7,p8,p9,p10,p11,p12, obs);
  transpose_kernel<<<dim3(11,48), dim3(32,8), 0, stream>>>(w_ih0, wT);
  ig0_kernel<<<dim3(6, T_STEPS/TTILE), 256, 0, stream>>>(wT, obs, b_ih0, ig0);
  init_kernel<<<1, 512, 0, stream>>>(hid, ring0, ring1);
  seq_kernel<<<96, 256, 0, stream>>>(ig0, w_hh0, b_n0, w_ih1, w_hh1, b_ih1, b_n1,
                                     ring0, ring1, cntB, h1a, out);
  mlp_kernel<<<T_STEPS/8, 64, 0, stream>>>(h1a, mw0, mb0, mw1, mb1, mw2, mb2, out);
}

// Round 10
// 27629.236 us; speedup vs baseline: 1.5678x; 1.2519x over previous
//
#include <hip/hip_runtime.h>
#include <math.h>

// ---------------------------------------------------------------------------
// DefaultHumanoidGRUCritic on MI355X — round 10
//
// Round-9 verdict: weights resident (VGPR=132) but time flat -> comm round
// binds. FETCH scales with WG count (staging atomics), and the A/B two-chain
// coupling compounds jitter. Round-10:
//   * STAGE FUSION: each WG computes h0[k] AND h1[k-1] per iteration; the
//     one staged pair (h0[k-1], h1[k-2]) feeds both. A<->B coupling gone;
//     max inter-WG skew 1 iter -> ring0 16 slots (128KB total, LLC-hot),
//     throttle deleted.
//   * 16B CONSUMER LOADS: producer still 8B atomic (tag,val); consumer reads
//     2 pairs/load via global_load_dwordx4 sc0 sc1 (coherence-point load);
//     each 8B half independently tag-verified -> torn halves detected.
//     ~4x fewer staging requests/step.
//   * 64 WGs x 384 thr: tid 0-127 -> 8 h0 els (16 lanes); tid 128-383 ->
//     8 h1 els (32 lanes, ih|hh halves). 96 weight floats/lane PINNED
//     (r9-proven: 96KB pad + waves_per_eu(1,2) + pin4).
//   * keep: 1 barrier/iter, parity LDS double-buffer, ig0 prefetch 1 ahead.
// ---------------------------------------------------------------------------

#define T_STEPS 16384
#define IN_DIM 341
#define HID 512
#define G3 1536
#define TTILE 16
#define R0 16
#define R0M (R0-1)
#define R1 16
#define R1M (R1-1)

typedef unsigned int v4u __attribute__((ext_vector_type(4)));

__device__ __forceinline__ float dot4(float4 a, float4 b) {
  return fmaf(a.x, b.x, fmaf(a.y, b.y, fmaf(a.z, b.z, a.w * b.w)));
}
__device__ __forceinline__ float fast_sigmoid(float x) {
  return __builtin_amdgcn_rcpf(1.0f + __expf(-x));
}
__device__ __forceinline__ float fast_tanh(float x) {
  return fmaf(-2.0f, __builtin_amdgcn_rcpf(1.0f + __expf(2.0f * x)), 1.0f);
}
__device__ __forceinline__ void st_rlx64(unsigned long long* p, unsigned long long v) {
  __hip_atomic_store(p, v, __ATOMIC_RELAXED, __HIP_MEMORY_SCOPE_AGENT);
}
__device__ __forceinline__ unsigned long long pack_tv(unsigned tag, float v) {
  return ((unsigned long long)tag << 32) | (unsigned long long)__float_as_uint(v);
}
__device__ __forceinline__ void pin4(float4& v) {
  asm volatile("" : "+v"(v.x), "+v"(v.y), "+v"(v.z), "+v"(v.w));
}
// coherence-point 16B load: two (val,tag) pairs. sc0 sc1 = system-scope load
// semantics on gfx940+ (forced miss to the coherence point); each 8B half is
// written by an 8B atomic store and is tag-verified independently by callers.
__device__ __forceinline__ v4u ld16(const unsigned long long* p) {
  v4u r;
  asm volatile("global_load_dwordx4 %0, %1, off sc0 sc1\n\ts_waitcnt vmcnt(0)"
               : "=v"(r) : "v"(p) : "memory");
  return r;
}
__device__ __forceinline__ void ld16x2(const unsigned long long* p0,
                                       const unsigned long long* p1,
                                       v4u& a, v4u& b) {
  asm volatile("global_load_dwordx4 %0, %2, off sc0 sc1\n\t"
               "global_load_dwordx4 %1, %3, off sc0 sc1\n\t"
               "s_waitcnt vmcnt(0)"
               : "=v"(a), "=v"(b) : "v"(p0), "v"(p1) : "memory");
}

// ---- k0: concat observations ----------------------------------------------
__global__ __launch_bounds__(384) void concat_kernel(
    const float* __restrict__ p0, const float* __restrict__ p1,
    const float* __restrict__ p2, const float* __restrict__ p3,
    const float* __restrict__ p4, const float* __restrict__ p5,
    const float* __restrict__ p6, const float* __restrict__ p7,
    const float* __restrict__ p8, const float* __restrict__ p9,
    const float* __restrict__ p10, const float* __restrict__ p11,
    const float* __restrict__ p12, float* __restrict__ obs) {
  int t = blockIdx.x;
  int k = threadIdx.x;
  if (k >= IN_DIM) return;
  float v;
  if (k < 21)       v = p0[t*21 + k];
  else if (k < 42)  v = p1[t*21 + (k-21)];
  else if (k < 202) v = p2[t*160 + (k-42)];
  else if (k < 298) v = p3[t*96 + (k-202)];
  else if (k < 301) v = p4[t*3 + (k-298)];
  else if (k < 304) v = p5[t*3 + (k-301)];
  else if (k < 325) v = p6[t*21 + (k-304)];
  else if (k < 328) v = p7[t*3 + (k-325)];
  else if (k < 332) v = p8[t*4 + (k-328)];
  else if (k < 335) v = p9[t*3 + (k-332)];
  else if (k < 338) v = p10[t*3 + (k-335)];
  else if (k < 340) v = p11[t*2 + (k-338)];
  else              v = p12[t];
  obs[(size_t)t*IN_DIM + k] = v;
}

// ---- k1: transpose w_ih0 ---------------------------------------------------
__global__ __launch_bounds__(256) void transpose_kernel(const float* __restrict__ w,
                                                        float* __restrict__ wT) {
  __shared__ float tile[32][33];
  int tx = threadIdx.x;  // 32
  int ty = threadIdx.y;  // 8
  int k = blockIdx.x*32 + tx;
#pragma unroll
  for (int jj = 0; jj < 4; jj++) {
    int r = blockIdx.y*32 + ty*4 + jj;
    tile[ty*4+jj][tx] = (k < IN_DIM) ? w[(size_t)r*IN_DIM + k] : 0.f;
  }
  __syncthreads();
#pragma unroll
  for (int jj = 0; jj < 4; jj++) {
    int kk = blockIdx.x*32 + ty*4 + jj;
    if (kk < IN_DIM) wT[(size_t)kk*G3 + blockIdx.y*32 + tx] = tile[tx][ty*4+jj];
  }
}

// ---- k2: IG0 = obs @ w_ih0^T + b_ih0 --------------------------------------
__global__ __launch_bounds__(256) void ig0_kernel(const float* __restrict__ wT,
                                                  const float* __restrict__ obs,
                                                  const float* __restrict__ b_ih0,
                                                  float* __restrict__ ig0) {
  int o = blockIdx.x*256 + threadIdx.x;
  int t0 = blockIdx.y * TTILE;
  float acc[TTILE];
  float b = b_ih0[o];
#pragma unroll
  for (int tt = 0; tt < TTILE; tt++) acc[tt] = b;
  for (int k = 0; k < IN_DIM; k++) {
    float wv = wT[(size_t)k*G3 + o];
#pragma unroll
    for (int tt = 0; tt < TTILE; tt++)
      acc[tt] = fmaf(obs[(size_t)(t0+tt)*IN_DIM + k], wv, acc[tt]);
  }
#pragma unroll
  for (int tt = 0; tt < TTILE; tt++)
    ig0[(size_t)(t0+tt)*G3 + o] = acc[tt];
}

// ---- k_init: seed ring slot 0 with tagged initial hidden -------------------
__global__ __launch_bounds__(512) void init_kernel(const float* __restrict__ hid,
                                                   unsigned long long* ring0,
                                                   unsigned long long* ring1) {
  int e = threadIdx.x;
  st_rlx64(&ring0[e], pack_tv(0u, hid[e]));
  st_rlx64(&ring1[e], pack_tv(0u, hid[HID + e]));
}

// ---- k3: fused sequential GRU scan ----------------------------------------
// 64 WGs x 384 threads, 1 block/CU. Iteration k (k = 0..T inclusive):
//   stage h0[k-1] (ring0 slot k&15, tag k) and h1[k-2] (ring1 slot (k-1)&15,
//   tag k-1); compute h0[k] (tid<128, if k<T) and h1[k-1] (tid>=128, if k>=1);
//   publish h0[k] -> ring0 slot (k+1)&15 tag k+1, h1[k-1] -> ring1 slot k&15
//   tag k. Convention: h^(t) lives at slot (t+1)&M with tag t+1; initial
//   hidden seeded at slot 0 tag 0.
__global__ __launch_bounds__(384)
__attribute__((amdgpu_waves_per_eu(1, 2)))
void seq_kernel(
    const float* __restrict__ ig0, const float* __restrict__ w_hh0,
    const float* __restrict__ b_n0, const float* __restrict__ w_ih1,
    const float* __restrict__ w_hh1, const float* __restrict__ b_ih1,
    const float* __restrict__ b_n1,
    unsigned long long* ring0, unsigned long long* ring1,
    float* __restrict__ h1a, float* __restrict__ d_out) {
  __shared__ float hbuf0[2][HID];
  __shared__ float hbuf1[2][HID];
  __shared__ float igbuf[2][24];
  __shared__ float vpad[24576];   // 96KB: occupancy calc -> 1 block/CU
  const int tid = threadIdx.x;
  const int wg = blockIdx.x;
  if (d_out == nullptr) {         // never true; defeats LDS elision
    vpad[tid] = (float)tid;
    __syncthreads();
    h1a[tid] = vpad[383 - tid];
  }

  const bool roleA = (tid < 128);          // 8 h0 elements, 16 lanes each
  const int u = tid - 128;                 // role B: 8 h1 elements, 32 lanes
  const int g = roleA ? (tid >> 4) : (u >> 5);
  const int jj = roleA ? (tid & 15) : (u & 15);
  const int half = roleA ? 0 : ((u >> 4) & 1);   // B: 0=ih(h0), 1=hh(h1)
  const int j32 = roleA ? 0 : (u & 31);
  const int eg = wg*8 + g;
  const bool leadA = roleA && (jj == 0);
  const bool leadB = (!roleA) && (j32 == 0);

  // 24 float4 (96 floats) of weights per lane, loaded once, PINNED resident.
  const float* wsrc = roleA ? w_hh0 : (half ? w_hh1 : w_ih1);
  float4 W[24];
#pragma unroll
  for (int gate = 0; gate < 3; gate++) {
    const float4* row = (const float4*)(wsrc + (size_t)(gate*HID + eg)*HID);
#pragma unroll
    for (int i = 0; i < 8; i++) {
      W[gate*8+i] = row[jj + 16*i];
      pin4(W[gate*8+i]);
    }
  }
  float cr=0.f, cz=0.f, cn=0.f, bnl;
  if (roleA) {
    bnl = b_n0[eg];
  } else {
    cr = b_ih1[eg]; cz = b_ih1[512+eg]; cn = b_ih1[1024+eg]; bnl = b_n1[eg];
  }

  const int iggate = tid >> 3, ige = tid & 7;   // tid<24: ig prefetch lanes
  if (tid < 24) igbuf[0][tid] = ig0[(size_t)iggate*HID + wg*8 + ige];

  for (int k = 0; k <= T_STEPS; k++) {
    const int p = k & 1;
    // prefetch ig for h0[k+1] (plain cached load; LDS write after barrier)
    float igpre = 0.f;
    if (tid < 24) {
      int kk = (k+1 < T_STEPS) ? (k+1) : (T_STEPS-1);
      igpre = ig0[(size_t)kk*G3 + (size_t)iggate*HID + wg*8 + ige];
    }
    // ---- staging: 16B loads, 2 tag-verified pairs each ----
    const unsigned wk0 = (unsigned)k, wk1 = (unsigned)(k-1);
    if (k == 0) {
      if (tid < 256) {
        const unsigned long long* pa = ring0 + 2*tid;
        v4u a = ld16(pa);
        while (a.y != wk0 || a.w != wk0) { __builtin_amdgcn_s_sleep(1); a = ld16(pa); }
        ((float2*)hbuf0[p])[tid] =
            make_float2(__uint_as_float(a.x), __uint_as_float(a.z));
      }
    } else {
      const unsigned long long* pa = ring0 + (size_t)(k & R0M)*HID + 2*tid;
      const unsigned long long* pb = ring1 + (size_t)((k-1) & R1M)*HID + 2*(tid-128);
      if (tid < 128) {
        v4u a = ld16(pa);
        while (a.y != wk0 || a.w != wk0) { __builtin_amdgcn_s_sleep(1); a = ld16(pa); }
        ((float2*)hbuf0[p])[tid] =
            make_float2(__uint_as_float(a.x), __uint_as_float(a.z));
      } else if (tid < 256) {
        v4u a, b;
        ld16x2(pa, pb, a, b);   // both probes in flight together
        while (a.y != wk0 || a.w != wk0) { __builtin_amdgcn_s_sleep(1); a = ld16(pa); }
        while (b.y != wk1 || b.w != wk1) { __builtin_amdgcn_s_sleep(1); b = ld16(pb); }
        ((float2*)hbuf0[p])[tid] =
            make_float2(__uint_as_float(a.x), __uint_as_float(a.z));
        ((float2*)hbuf1[p])[tid-128] =
            make_float2(__uint_as_float(b.x), __uint_as_float(b.z));
      } else {
        v4u b = ld16(pb);
        while (b.y != wk1 || b.w != wk1) { __builtin_amdgcn_s_sleep(1); b = ld16(pb); }
        ((float2*)hbuf1[p])[tid-128] =
            make_float2(__uint_as_float(b.x), __uint_as_float(b.z));
      }
    }
    __syncthreads();   // the only barrier per iteration
    // ---- compute ----
    const bool act = roleA ? (k < T_STEPS) : (k >= 1);
    if (act) {
      const float4* hp = (roleA || half == 0) ? (const float4*)hbuf0[p]
                                              : (const float4*)hbuf1[p];
      float pr=0.f, pz=0.f, pn=0.f;
#pragma unroll
      for (int i = 0; i < 8; i++) {
        float4 hv = hp[jj + 16*i];   // words 4jj+64i: conflict-free (<=2-way)
        pr += dot4(W[i],hv); pz += dot4(W[8+i],hv); pn += dot4(W[16+i],hv);
      }
#pragma unroll
      for (int s = 1; s < 16; s <<= 1) {
        pr += __shfl_xor(pr, s, 16);
        pz += __shfl_xor(pz, s, 16);
        pn += __shfl_xor(pn, s, 16);
      }
      if (roleA) {
        if (leadA) {
          float r = fast_sigmoid(igbuf[p][g] + pr);
          float z = fast_sigmoid(igbuf[p][8+g] + pz);
          float n = fast_tanh(igbuf[p][16+g] + r*(pn + bnl));
          float hnew = n + z*(hbuf0[p][eg] - n);
          st_rlx64(&ring0[(size_t)((k+1) & R0M)*HID + eg],
                   pack_tv((unsigned)(k+1), hnew));
          if (k == T_STEPS-1) d_out[T_STEPS + eg] = hnew;
        }
      } else {
        // harvest hh-half sums (lane 16 of the 32-lane group)
        float qr = __shfl(pr, 16, 32);
        float qz = __shfl(pz, 16, 32);
        float qn = __shfl(pn, 16, 32);
        if (leadB) {
          float r = fast_sigmoid(pr + cr + qr);
          float z = fast_sigmoid(pz + cz + qz);
          float n = fast_tanh(pn + cn + r*(qn + bnl));
          float hnew = n + z*(hbuf1[p][eg] - n);
          st_rlx64(&ring1[(size_t)(k & R1M)*HID + eg],
                   pack_tv((unsigned)k, hnew));
          h1a[(size_t)(k-1)*HID + eg] = hnew;   // plain store for the MLP
          if (k == T_STEPS) d_out[T_STEPS + HID + eg] = hnew;
        }
      }
    }
    if (tid < 24) igbuf[p ^ 1][tid] = igpre;
  }
}

// ---- k4: batched MLP head --------------------------------------------------
__global__ __launch_bounds__(64) void mlp_kernel(
    const float* __restrict__ h1_all, const float* __restrict__ mw0,
    const float* __restrict__ mb0, const float* __restrict__ mw1,
    const float* __restrict__ mb1, const float* __restrict__ mw2,
    const float* __restrict__ mb2, float* __restrict__ out) {
  const int l = threadIdx.x;
  const int t0 = blockIdx.x * 8;
  __shared__ float v0s[8][64];
  float acc[8];
#pragma unroll
  for (int tt = 0; tt < 8; tt++) acc[tt] = mb0[l];
  const float4* w = (const float4*)(mw0 + (size_t)l*512);
#pragma unroll 4
  for (int i = 0; i < 128; i++) {
    float4 a = w[i];
#pragma unroll
    for (int tt = 0; tt < 8; tt++) {
      float4 b = ((const float4*)(h1_all + (size_t)(t0+tt)*512))[i];
      acc[tt] = fmaf(a.x,b.x, fmaf(a.y,b.y, fmaf(a.z,b.z, fmaf(a.w,b.w, acc[tt]))));
    }
  }
#pragma unroll
  for (int tt = 0; tt < 8; tt++) v0s[tt][l] = fmaxf(acc[tt], 0.f);
  __syncthreads();
  float acc1[8];
#pragma unroll
  for (int tt = 0; tt < 8; tt++) acc1[tt] = mb1[l];
  const float* w1 = mw1 + (size_t)l*64;
  for (int jj = 0; jj < 64; jj++) {
    float wv = w1[jj];
#pragma unroll
    for (int tt = 0; tt < 8; tt++) acc1[tt] = fmaf(wv, v0s[tt][jj], acc1[tt]);
  }
  float w2 = mw2[l];
  float bb = mb2[0];
#pragma unroll
  for (int tt = 0; tt < 8; tt++) {
    float y = w2 * fmaxf(acc1[tt], 0.f);
#pragma unroll
    for (int s = 32; s > 0; s >>= 1) y += __shfl_down(y, s, 64);
    if (l == 0) out[t0+tt] = y + bb;
  }
}

// ---------------------------------------------------------------------------
extern "C" void kernel_launch(void* const* d_in, const int* in_sizes, int n_in,
                              void* d_out, int out_size, void* d_ws, size_t ws_size,
                              hipStream_t stream) {
  const float* p0  = (const float*)d_in[0];
  const float* p1  = (const float*)d_in[1];
  const float* p2  = (const float*)d_in[2];
  const float* p3  = (const float*)d_in[3];
  const float* p4  = (const float*)d_in[4];
  const float* p5  = (const float*)d_in[5];
  const float* p6  = (const float*)d_in[6];
  const float* p7  = (const float*)d_in[7];
  const float* p8  = (const float*)d_in[8];
  const float* p9  = (const float*)d_in[9];
  const float* p10 = (const float*)d_in[10];
  const float* p11 = (const float*)d_in[11];
  const float* p12 = (const float*)d_in[12];
  const float* hid   = (const float*)d_in[13];
  const float* w_ih0 = (const float*)d_in[14];
  const float* w_hh0 = (const float*)d_in[15];
  const float* b_ih0 = (const float*)d_in[16];
  const float* b_n0  = (const float*)d_in[17];
  const float* w_ih1 = (const float*)d_in[18];
  const float* w_hh1 = (const float*)d_in[19];
  const float* b_ih1 = (const float*)d_in[20];
  const float* b_n1  = (const float*)d_in[21];
  const float* mw0 = (const float*)d_in[22];
  const float* mb0 = (const float*)d_in[23];
  const float* mw1 = (const float*)d_in[24];
  const float* mb1 = (const float*)d_in[25];
  const float* mw2 = (const float*)d_in[26];
  const float* mb2 = (const float*)d_in[27];
  float* out = (float*)d_out;

  // workspace: ig0 | ring0 | ring1 | h1a  (obs/wT alias h1a region)
  char* base = (char*)d_ws;
  const size_t IG0_B = (size_t)T_STEPS*G3*4;     // 100,663,296
  const size_t R0_B  = (size_t)R0*HID*8;         //      65,536
  const size_t R1_B  = (size_t)R1*HID*8;         //      65,536
  const size_t H1A_B = (size_t)T_STEPS*HID*4;    //  33,554,432
  float* ig0 = (float*)base;
  unsigned long long* ring0 = (unsigned long long*)(base + IG0_B);
  unsigned long long* ring1 = (unsigned long long*)(base + IG0_B + R0_B);
  float* h1a = (float*)(base + IG0_B + R0_B + R1_B);
  float* obs = h1a;                                              // alias
  float* wT  = (float*)((char*)h1a + (size_t)T_STEPS*IN_DIM*4);  // alias
  if (ws_size < IG0_B + R0_B + R1_B + H1A_B) return;

  concat_kernel<<<T_STEPS, 384, 0, stream>>>(p0,p1,p2,p3,p4,p5,p6,p7,p8,p9,p10,p11,p12, obs);
  transpose_kernel<<<dim3(11,48), dim3(32,8), 0, stream>>>(w_ih0, wT);
  ig0_kernel<<<dim3(6, T_STEPS/TTILE), 256, 0, stream>>>(wT, obs, b_ih0, ig0);
  init_kernel<<<1, 512, 0, stream>>>(hid, ring0, ring1);
  seq_kernel<<<64, 384, 0, stream>>>(ig0, w_hh0, b_n0, w_ih1, w_hh1, b_ih1, b_n1,
                                     ring0, ring1, h1a, out);
  mlp_kernel<<<T_STEPS/8, 64, 0, stream>>>(h1a, mw0, mb0, mw1, mb1, mw2, mb2, out);
}